// Round 13
// baseline (270.426 us; speedup 1.0000x reference)
//
#include <hip/hip_runtime.h>
#include <hip/hip_fp16.h>

// FlowLayer: B=2, CIN=256, COUT=128, H=W=128, iters=24.
// s = sum_{k=0..24} S^k m = m + S(t + S t),  t = (I+S^2)(I+S^4)(I+S^8+S^16) m
// 11 x S^2 (16-tap) + 2 x S (4-tap). S^2 kernel: 32 lanes per TWO slots,
// x-adjacent tap pairs (one load instr each), 16 loads in flight/wave,
// shfl_xor(16) combines x0/x1 partial sums. launch_bounds(256,4) caps VGPR.

#define PC 4194304
#define HW 16384

struct CoefC { int4 o0; float4 w0; int4 o1; float4 w1; int4 o2; float4 w2; int4 o3; float4 w3; };
struct Coef1 { int4 oa; float4 wa; };

struct alignas(16) H8 { __half2 h[4]; };
struct alignas(8)  H4 { __half2 h[2]; };
typedef _Float16 f16x8 __attribute__((ext_vector_type(8)));
typedef float f32x4 __attribute__((ext_vector_type(4)));

__device__ __forceinline__ float sigf(float v) { return 1.0f / (1.0f + __expf(-v)); }

__device__ __forceinline__ H8 f8h(const float* f) {
  H8 r;
#pragma unroll
  for (int i = 0; i < 4; i++) r.h[i] = __floats2half2_rn(f[2*i], f[2*i+1]);
  return r;
}
__device__ __forceinline__ f16x8 ld8(const __half* p) { return *(const f16x8*)p; }
__device__ __forceinline__ void fma8(float* a, const f16x8& v, float w) {
#pragma unroll
  for (int i = 0; i < 8; i++) a[i] = fmaf(w, (float)v[i], a[i]);   // v_fma_mix
}
__device__ __forceinline__ void fma4g(float* a, const f16x8& v0, const f16x8& v1,
                                      const f16x8& v2, const f16x8& v3, float4 w) {
  fma8(a, v0, w.x); fma8(a, v1, w.y); fma8(a, v2, w.z); fma8(a, v3, w.w);
}

// XCD-aware slot base (65536-slot space: 4 images of 16384; image -> XCD pair).
template <int SPB>
__device__ __forceinline__ int slot_base_64k(int bid) {
  int xcd = bid & 7;
  int i = xcd >> 1;
  int half = xcd & 1;
  int sub = bid >> 3;
  return (i >> 1) * 32768 + (i & 1) * 16384 + half * 8192 + sub * SPB;
}
// 32768-slot space (2 batches): image b -> 4 XCDs, each a quarter-image.
template <int SPB>
__device__ __forceinline__ int slot_base_32k(int bid) {
  int xcd = bid & 7;
  int b = xcd >> 2;
  int q = xcd & 3;
  int sub = bid >> 3;
  return b * 16384 + q * 4096 + sub * SPB;
}

// ---------------- per-pixel bilinear stencil
__device__ __forceinline__ void stencil(const float* __restrict__ g, float sgn, int pix,
                                        int4& op, float4& wt) {
  int b = pix >> 14, hw = pix & 16383;
  int h = hw >> 7, w = hw & 127;
  float gx = g[(size_t)(b * 2 + 0) * HW + hw];
  float gy = g[(size_t)(b * 2 + 1) * HW + hw];
  float xp = (float)w + sgn * gx;
  float yp = (float)h + sgn * gy;
  float x0f = floorf(xp), y0f = floorf(yp);
  float fx = xp - x0f, fy = yp - y0f;
  int x0 = (int)x0f, y0 = (int)y0f;
  int x1 = x0 + 1, y1 = y0 + 1;
  bool vx0 = (x0 >= 0) && (x0 <= 127);
  bool vx1 = (x1 >= 0) && (x1 <= 127);
  bool vy0 = (y0 >= 0) && (y0 <= 127);
  bool vy1 = (y1 >= 0) && (y1 <= 127);
  int x0c = min(max(x0, 0), 127), x1c = min(max(x1, 0), 127);
  int y0c = min(max(y0, 0), 127), y1c = min(max(y1, 0), 127);
  int bb = b << 14;
  op.x = bb + y0c * 128 + x0c;
  op.y = bb + y0c * 128 + x1c;
  op.z = bb + y1c * 128 + x0c;
  op.w = bb + y1c * 128 + x1c;
  wt.x = (vx0 && vy0) ? (1.f - fx) * (1.f - fy) : 0.f;
  wt.y = (vx1 && vy0) ? fx * (1.f - fy) : 0.f;
  wt.z = (vx0 && vy1) ? (1.f - fx) * fy : 0.f;
  wt.w = (vx1 && vy1) ? fx * fy : 0.f;
}

__device__ __forceinline__ int4 shl7(int4 v) {
  return make_int4(v.x << 7, v.y << 7, v.z << 7, v.w << 7);
}
__device__ __forceinline__ float4 scale4(float4 v, float s) {
  return make_float4(v.x * s, v.y * s, v.z * s, v.w * s);
}

// ---------------- merged prep: stencil tables + weight conversions
__global__ __launch_bounds__(256) void prep_kernel(const float* __restrict__ grads,
                                                   Coef1* __restrict__ c1,
                                                   CoefC* __restrict__ c2,
                                                   const float* __restrict__ mdw,
                                                   const float* __restrict__ pdw,
                                                   const float* __restrict__ w1,
                                                   const float* __restrict__ w2,
                                                   const float* __restrict__ mpw,
                                                   const float* __restrict__ ppw,
                                                   float* __restrict__ wdwT,
                                                   float* __restrict__ pdwT,
                                                   __half* __restrict__ wT16,
                                                   __half* __restrict__ wpw1,
                                                   __half* __restrict__ wpw2) {
  int bid = blockIdx.x;
  int tid = threadIdx.x;
  if (bid < 256) {
    int idx = bid * 256 + tid;
    int chain = idx >> 15;
    int p = idx & 32767;
    float sgn = chain ? -3.96875f : 3.96875f;   // 63.5*1.5/24
    int4 op; float4 ow;
    stencil(grads, sgn, p, op, ow);
    Coef1 a; a.oa = shl7(op); a.wa = ow;
    c1[idx] = a;
    CoefC c;
    int4 o2; float4 nw;
    stencil(grads, sgn, op.x, o2, nw); c.o0 = shl7(o2); c.w0 = scale4(nw, ow.x);
    stencil(grads, sgn, op.y, o2, nw); c.o1 = shl7(o2); c.w1 = scale4(nw, ow.y);
    stencil(grads, sgn, op.z, o2, nw); c.o2 = shl7(o2); c.w2 = scale4(nw, ow.z);
    stencil(grads, sgn, op.w, o2, nw); c.o3 = shl7(o2); c.w3 = scale4(nw, ow.w);
    c2[idx] = c;
  } else {
    int i = (bid - 256) * 256 + tid;
    if (i < 65536) {
      int co = i >> 8, ci = i & 255;
      float v = (co < 128) ? w1[co * 256 + ci] : w2[(size_t)(co - 128) * 256 + ci];
      wT16[i] = __float2half(v);
    } else if (i < 98304) {
      int j = i - 65536;
      wpw1[j] = __float2half(mpw[j]);
    } else if (i < 114688) {
      int j = i - 98304;
      wpw2[j] = __float2half(ppw[j]);
    } else if (i < 116992) {
      int j = i - 114688;
      int ch = j / 9, t = j % 9;
      wdwT[t * 256 + ch] = mdw[j];
    } else if (i < 118144) {
      int j = i - 116992;
      int ch = j / 9, t = j % 9;
      pdwT[t * 128 + ch] = pdw[j];
    }
  }
}

// ---------------- conv1x1 via f16 MFMA
__global__ __launch_bounds__(256) void conv1_kernel(const float* __restrict__ x,
                                                    const __half* __restrict__ wT16,
                                                    __half* __restrict__ mOut) {
  __shared__ __align__(16) char As[4096];
  __shared__ __align__(16) char Bs[16384];
  int tid = threadIdx.x;
  int p0 = blockIdx.x * 64;
  int b = p0 >> 14;
  int hw0 = p0 & 16383;
  int wv = tid >> 6, ln = tid & 63;
  int hi = ln >> 4, lo = ln & 15;
  f32x4 acc[4][4] = {};
  const float* xb = x + (size_t)b * 256 * HW + hw0;
  int apx = tid & 63, ac8 = (tid >> 6) * 8;
  int abyte = (apx * 64 + ac8 * 2) ^ ((apx & 3) << 4);
  for (int k = 0; k < 256; k += 32) {
    f16x8 av;
#pragma unroll
    for (int j = 0; j < 8; j++) av[j] = (_Float16)xb[(size_t)(k + ac8 + j) * HW + apx];
    if (k) __syncthreads();
    *(f16x8*)(As + abyte) = av;
    {
      const __half* src = wT16 + (size_t)tid * 256 + k;
#pragma unroll
      for (int s = 0; s < 4; s++) {
        f16x8 bv = *(const f16x8*)(src + s * 8);
        int byte = (tid * 64 + s * 16) ^ ((tid & 3) << 4);
        *(f16x8*)(Bs + byte) = bv;
      }
    }
    __syncthreads();
    f16x8 aF[4], bF[4];
#pragma unroll
    for (int m = 0; m < 4; m++) {
      int px = m * 16 + lo;
      int byte = (px * 64 + hi * 16) ^ ((px & 3) << 4);
      aF[m] = *(const f16x8*)(As + byte);
    }
#pragma unroll
    for (int n = 0; n < 4; n++) {
      int co = wv * 64 + n * 16 + lo;
      int byte = (co * 64 + hi * 16) ^ ((co & 3) << 4);
      bF[n] = *(const f16x8*)(Bs + byte);
    }
#pragma unroll
    for (int m = 0; m < 4; m++)
#pragma unroll
      for (int n = 0; n < 4; n++)
        acc[m][n] = __builtin_amdgcn_mfma_f32_16x16x32_f16(aF[m], bF[n], acc[m][n], 0, 0, 0);
  }
  size_t base = (wv >= 2) ? (size_t)PC : 0;
  int col0 = (wv & 1) * 64;
#pragma unroll
  for (int m = 0; m < 4; m++)
#pragma unroll
    for (int n = 0; n < 4; n++) {
      int col = col0 + n * 16 + lo;
#pragma unroll
      for (int rr = 0; rr < 4; rr++) {
        int px = p0 + m * 16 + hi * 4 + rr;
        mOut[base + (size_t)px * 128 + col] = __float2half(sigf(acc[m][n][rr]));
      }
    }
}

// ---------------- S^2 (16 taps as 8 pairs), 32 lanes handle TWO slots.
// Lanes 0-15 take x0 rows, 16-31 x1 rows; 16 loads in flight before first use.
// ACC 0: none; 1: accOut = accAdd + res; 2: accOut += res; 3: acc only, no state write
template <int ACC>
__global__ __launch_bounds__(256, 4) void s2_kernel(const __half* __restrict__ inb,
                                                    __half* __restrict__ outb,
                                                    const __half* __restrict__ accAdd,
                                                    __half* __restrict__ accOut,
                                                    const uint4* __restrict__ c2tab) {
  __shared__ uint4 cs[128];                  // 16 slots x 8 uint4
  int tid = threadIdx.x;
  int slot0 = slot_base_64k<16>(blockIdx.x);
  if (tid < 128) cs[tid] = c2tab[(size_t)slot0 * 8 + tid];
  __syncthreads();
  int sg = tid >> 5;                         // 0..7 -> slots sg, sg+8
  int lane = tid & 31;
  int side = lane >> 4;                      // 0: x0 rows, 1: x1 rows
  int ch = (lane & 15) << 3;
  const CoefC cA = ((const CoefC*)cs)[sg];
  const CoefC cB = ((const CoefC*)cs)[sg + 8];
  int slotA = slot0 + sg;
  int slotB = slot0 + sg + 8;
  int chain = slot0 >> 15;                   // whole block in one image
  size_t cb = (size_t)chain * PC;
  const __half* base = inb + cb + ch;
  int rowA = ((slotA & 32767) << 7) + ch;
  int rowB = ((slotB & 32767) << 7) + ch;

  int aO0 = side ? cA.o0.y : cA.o0.x;  float aW0 = side ? cA.w0.y : cA.w0.x;
  int aO1 = side ? cA.o0.w : cA.o0.z;  float aW1 = side ? cA.w0.w : cA.w0.z;
  int aO2 = side ? cA.o1.y : cA.o1.x;  float aW2 = side ? cA.w1.y : cA.w1.x;
  int aO3 = side ? cA.o1.w : cA.o1.z;  float aW3 = side ? cA.w1.w : cA.w1.z;
  int aO4 = side ? cA.o2.y : cA.o2.x;  float aW4 = side ? cA.w2.y : cA.w2.x;
  int aO5 = side ? cA.o2.w : cA.o2.z;  float aW5 = side ? cA.w2.w : cA.w2.z;
  int aO6 = side ? cA.o3.y : cA.o3.x;  float aW6 = side ? cA.w3.y : cA.w3.x;
  int aO7 = side ? cA.o3.w : cA.o3.z;  float aW7 = side ? cA.w3.w : cA.w3.z;
  int bO0 = side ? cB.o0.y : cB.o0.x;  float bW0 = side ? cB.w0.y : cB.w0.x;
  int bO1 = side ? cB.o0.w : cB.o0.z;  float bW1 = side ? cB.w0.w : cB.w0.z;
  int bO2 = side ? cB.o1.y : cB.o1.x;  float bW2 = side ? cB.w1.y : cB.w1.x;
  int bO3 = side ? cB.o1.w : cB.o1.z;  float bW3 = side ? cB.w1.w : cB.w1.z;
  int bO4 = side ? cB.o2.y : cB.o2.x;  float bW4 = side ? cB.w2.y : cB.w2.x;
  int bO5 = side ? cB.o2.w : cB.o2.z;  float bW5 = side ? cB.w2.w : cB.w2.z;
  int bO6 = side ? cB.o3.y : cB.o3.x;  float bW6 = side ? cB.w3.y : cB.w3.x;
  int bO7 = side ? cB.o3.w : cB.o3.z;  float bW7 = side ? cB.w3.w : cB.w3.z;

  f16x8 a0 = ld8(base + aO0), a1 = ld8(base + aO1), a2v = ld8(base + aO2), a3 = ld8(base + aO3);
  f16x8 a4 = ld8(base + aO4), a5 = ld8(base + aO5), a6 = ld8(base + aO6), a7 = ld8(base + aO7);
  f16x8 b0 = ld8(base + bO0), b1 = ld8(base + bO1), b2 = ld8(base + bO2), b3 = ld8(base + bO3);
  f16x8 b4 = ld8(base + bO4), b5 = ld8(base + bO5), b6 = ld8(base + bO6), b7 = ld8(base + bO7);

  float sA[8] = {}, sB[8] = {};
  fma8(sA, a0, aW0); fma8(sA, a1, aW1); fma8(sA, a2v, aW2); fma8(sA, a3, aW3);
  fma8(sA, a4, aW4); fma8(sA, a5, aW5); fma8(sA, a6, aW6); fma8(sA, a7, aW7);
  fma8(sB, b0, bW0); fma8(sB, b1, bW1); fma8(sB, b2, bW2); fma8(sB, b3, bW3);
  fma8(sB, b4, bW4); fma8(sB, b5, bW5); fma8(sB, b6, bW6); fma8(sB, b7, bW7);
#pragma unroll
  for (int i = 0; i < 8; i++) {
    sA[i] += __shfl_xor(sA[i], 16);
    sB[i] += __shfl_xor(sB[i], 16);
  }

  if (side == 0) {
    if (ACC != 3) {
      *(H8*)(outb + cb + rowA) = f8h(sA);
      *(H8*)(outb + cb + rowB) = f8h(sB);
    }
    if (ACC == 1 || ACC == 3) {
      f16x8 vA = ld8(accAdd + cb + rowA);
      f16x8 vB = ld8(accAdd + cb + rowB);
      float fA[8], fB[8];
#pragma unroll
      for (int i = 0; i < 8; i++) { fA[i] = sA[i] + (float)vA[i]; fB[i] = sB[i] + (float)vB[i]; }
      *(H8*)(accOut + cb + rowA) = f8h(fA);
      *(H8*)(accOut + cb + rowB) = f8h(fB);
    } else if (ACC == 2) {
      f16x8 vA = ld8(accOut + cb + rowA);
      f16x8 vB = ld8(accOut + cb + rowB);
      float fA[8], fB[8];
#pragma unroll
      for (int i = 0; i < 8; i++) { fA[i] = sA[i] + (float)vA[i]; fB[i] = sB[i] + (float)vB[i]; }
      *(H8*)(accOut + cb + rowA) = f8h(fA);
      *(H8*)(accOut + cb + rowB) = f8h(fB);
    }
  }
}

// ---------------- single-S pass (4 taps). MODE 0: out = own + S in
// MODE 1: out = sigmoid(own + S in)
template <int MODE>
__global__ __launch_bounds__(256) void s1_kernel(const __half* __restrict__ tin,
                                                 const __half* __restrict__ own,
                                                 __half* __restrict__ outb,
                                                 const uint4* __restrict__ c1tab) {
  __shared__ uint4 cs[32];
  int tid = threadIdx.x;
  int slot0 = slot_base_64k<16>(blockIdx.x);
  if (tid < 32) cs[tid] = c1tab[(size_t)slot0 * 2 + tid];
  __syncthreads();
  const Coef1 a = ((const Coef1*)cs)[tid >> 4];
  int slot = slot0 + (tid >> 4);
  int ch = (tid & 15) << 3;
  int chain = slot >> 15;
  size_t cb = (size_t)chain * PC;
  const __half* base = tin + cb + ch;
  int rowel = ((slot & 32767) << 7) + ch;
  f16x8 t0 = ld8(base + a.oa.x), t1 = ld8(base + a.oa.y),
        t2 = ld8(base + a.oa.z), t3 = ld8(base + a.oa.w);
  f16x8 ov = ld8(own + cb + rowel);
  float r[8] = {};
  fma4g(r, t0, t1, t2, t3, a.wa);
  if (MODE == 0) {
#pragma unroll
    for (int i = 0; i < 8; i++) r[i] += (float)ov[i];
  } else {
#pragma unroll
    for (int i = 0; i < 8; i++) r[i] = sigf(r[i] + (float)ov[i]);
  }
  *(H8*)(outb + cb + rowel) = f8h(r);
}

// ---------------- depthwise 3x3, zero pad, XCD-local mapping, fma_mix
template <int C>
__global__ __launch_bounds__(256) void dw_kernel(const __half* __restrict__ in,
                                                 const float* __restrict__ wT,
                                                 __half* __restrict__ out) {
  int tid = threadIdx.x;
  constexpr int TPP = C / 8;
  constexpr int PPB = 256 / TPP;
  int slot = slot_base_32k<PPB>(blockIdx.x) + tid / TPP;
  int ch = (tid % TPP) * 8;
  int b = slot >> 14, h = (slot >> 7) & 127, w = slot & 127;
  const __half* src;
  int choff;
  if (C == 256) { src = in + ((ch < 128) ? 0 : (size_t)PC); choff = ch & 127; }
  else          { src = in; choff = ch; }
  float acc[8] = {};
#pragma unroll
  for (int t = 0; t < 9; t++) {
    int dy = t / 3 - 1, dx = t % 3 - 1;
    int yy = h + dy, xx = w + dx;
    if (yy < 0 || yy > 127 || xx < 0 || xx > 127) continue;
    int q = (b << 14) + yy * 128 + xx;
    f16x8 v = ld8(src + (size_t)q * 128 + choff);
    float4 wa = *(const float4*)(wT + t * C + ch);
    float4 wb = *(const float4*)(wT + t * C + ch + 4);
    acc[0] = fmaf(wa.x, (float)v[0], acc[0]);
    acc[1] = fmaf(wa.y, (float)v[1], acc[1]);
    acc[2] = fmaf(wa.z, (float)v[2], acc[2]);
    acc[3] = fmaf(wa.w, (float)v[3], acc[3]);
    acc[4] = fmaf(wb.x, (float)v[4], acc[4]);
    acc[5] = fmaf(wb.y, (float)v[5], acc[5]);
    acc[6] = fmaf(wb.z, (float)v[6], acc[6]);
    acc[7] = fmaf(wb.w, (float)v[7], acc[7]);
  }
  *(H8*)(out + (size_t)slot * C + ch) = f8h(acc);
}

// ---------------- pw1: [P]x[256] @ w[128co][256ci] -> fp16 channels-last [P][128]
__global__ __launch_bounds__(256) void pw1_kernel(const __half* __restrict__ in,
                                                  const __half* __restrict__ w16,
                                                  const float* __restrict__ bias,
                                                  __half* __restrict__ out) {
  int tid = threadIdx.x;
  int p0 = blockIdx.x * 64;
  int wv = tid >> 6, ln = tid & 63;
  int hi = ln >> 4, lo = ln & 15;
  int px = p0 + wv * 16 + lo;
  f32x4 acc[8] = {};
  for (int k = 0; k < 256; k += 32) {
    f16x8 bF = *(const f16x8*)(in + (size_t)px * 256 + k + hi * 8);
#pragma unroll
    for (int m = 0; m < 8; m++) {
      f16x8 aF = *(const f16x8*)(w16 + (size_t)(m * 16 + lo) * 256 + k + hi * 8);
      acc[m] = __builtin_amdgcn_mfma_f32_16x16x32_f16(aF, bF, acc[m], 0, 0, 0);
    }
  }
  int opx = p0 + wv * 16 + lo;
#pragma unroll
  for (int m = 0; m < 8; m++) {
    int co = m * 16 + hi * 4;
    float4 bv = *(const float4*)(bias + co);
    H4 hv;
    hv.h[0] = __floats2half2_rn(acc[m][0] + bv.x, acc[m][1] + bv.y);
    hv.h[1] = __floats2half2_rn(acc[m][2] + bv.z, acc[m][3] + bv.w);
    *(H4*)(out + (size_t)opx * 128 + co) = hv;
  }
}

// ---------------- pw2: [P]x[128] @ w[128co][128ci] -> f32 NCHW + bias
__global__ __launch_bounds__(256) void pw2_kernel(const __half* __restrict__ in,
                                                  const __half* __restrict__ w16,
                                                  const float* __restrict__ bias,
                                                  float* __restrict__ out) {
  int tid = threadIdx.x;
  int p0 = blockIdx.x * 64;
  int b = p0 >> 14;
  int hw0 = p0 & 16383;
  int wv = tid >> 6, ln = tid & 63;
  int hi = ln >> 4, lo = ln & 15;
  int co0 = wv * 32;
  f32x4 acc[4][2] = {};
  for (int k = 0; k < 128; k += 32) {
    f16x8 aF[4], bF[2];
#pragma unroll
    for (int m = 0; m < 4; m++)
      aF[m] = *(const f16x8*)(in + (size_t)(p0 + m * 16 + lo) * 128 + k + hi * 8);
#pragma unroll
    for (int n = 0; n < 2; n++)
      bF[n] = *(const f16x8*)(w16 + (size_t)(co0 + n * 16 + lo) * 128 + k + hi * 8);
#pragma unroll
    for (int m = 0; m < 4; m++)
#pragma unroll
      for (int n = 0; n < 2; n++)
        acc[m][n] = __builtin_amdgcn_mfma_f32_16x16x32_f16(aF[m], bF[n], acc[m][n], 0, 0, 0);
  }
#pragma unroll
  for (int m = 0; m < 4; m++)
#pragma unroll
    for (int n = 0; n < 2; n++) {
      int co = co0 + n * 16 + lo;
      float bb = bias[co];
      float4 v = {acc[m][n][0] + bb, acc[m][n][1] + bb, acc[m][n][2] + bb, acc[m][n][3] + bb};
      *(float4*)(out + (size_t)(b * 128 + co) * HW + hw0 + m * 16 + hi * 4) = v;
    }
}

extern "C" void kernel_launch(void* const* d_in, const int* in_sizes, int n_in,
                              void* d_out, int out_size, void* d_ws, size_t ws_size,
                              hipStream_t stream) {
  const float* x     = (const float*)d_in[0];
  const float* grads = (const float*)d_in[1];
  const float* w1    = (const float*)d_in[2];
  const float* w2    = (const float*)d_in[3];
  const float* mdw   = (const float*)d_in[4];
  const float* mpw   = (const float*)d_in[5];
  const float* mb    = (const float*)d_in[6];
  const float* pdw   = (const float*)d_in[7];
  const float* ppw   = (const float*)d_in[8];
  const float* pb    = (const float*)d_in[9];
  float* out = (float*)d_out;
  char* wsb = (char*)d_ws;

  __half* M  = (__half*)wsb;
  __half* A  = (__half*)(wsb + (size_t)16777216);
  __half* Bb = (__half*)(wsb + (size_t)33554432);
  __half* Pb = (__half*)(wsb + (size_t)50331648);
  __half* Qb = (__half*)(wsb + (size_t)67108864);
  CoefC* C2  = (CoefC*)(wsb + (size_t)83886080);
  Coef1* C1  = (Coef1*)(wsb + (size_t)92274688);
  __half* WT16 = (__half*)(wsb + (size_t)94371840);
  __half* WPW1 = (__half*)(wsb + (size_t)94502912);
  __half* WPW2 = (__half*)(wsb + (size_t)94568448);
  float* wdwT  = (float*)(wsb + (size_t)94601216);
  float* pdwT  = wdwT + 2304;

  const uint4* c2u = (const uint4*)C2;
  const uint4* c1u = (const uint4*)C1;

  prep_kernel<<<718, 256, 0, stream>>>(grads, C1, C2, mdw, pdw, w1, w2, mpw, ppw,
                                       wdwT, pdwT, WT16, WPW1, WPW2);
  conv1_kernel<<<512, 256, 0, stream>>>(x, WT16, M);

  // p = (I + S^8 + S^16) m   (P buffer)
  s2_kernel<0><<<4096, 256, 0, stream>>>(M,  A,  nullptr, nullptr, c2u);   // S^2 m
  s2_kernel<0><<<4096, 256, 0, stream>>>(A,  Bb, nullptr, nullptr, c2u);   // S^4
  s2_kernel<0><<<4096, 256, 0, stream>>>(Bb, A,  nullptr, nullptr, c2u);   // S^6
  s2_kernel<1><<<4096, 256, 0, stream>>>(A,  Bb, M,       Pb,      c2u);   // S^8 ; P=m+S^8m
  s2_kernel<0><<<4096, 256, 0, stream>>>(Bb, A,  nullptr, nullptr, c2u);   // S^10
  s2_kernel<0><<<4096, 256, 0, stream>>>(A,  Bb, nullptr, nullptr, c2u);   // S^12
  s2_kernel<0><<<4096, 256, 0, stream>>>(Bb, A,  nullptr, nullptr, c2u);   // S^14
  s2_kernel<2><<<4096, 256, 0, stream>>>(A,  Bb, nullptr, Pb,      c2u);   // S^16 ; P+=S^16m
  // q = (I + S^4) p ; t = (I + S^2) q
  s2_kernel<0><<<4096, 256, 0, stream>>>(Pb, A,  nullptr, nullptr, c2u);   // S^2 p
  s2_kernel<1><<<4096, 256, 0, stream>>>(A,  Bb, Pb,      Qb,      c2u);   // S^4 p ; Q=p+S^4p
  s2_kernel<3><<<4096, 256, 0, stream>>>(Qb, A,  Qb,      Pb,      c2u);   // t = q+S^2q (acc only)
  // s = sigmoid(m + S(t + S t)):  w = t + S t -> Bb ;  s = sigmoid(m + S w) -> A
  s1_kernel<0><<<4096, 256, 0, stream>>>(Pb, Pb, Bb, c1u);
  s1_kernel<1><<<4096, 256, 0, stream>>>(Bb, M,  A,  c1u);

  // merge stage
  __half* DW1 = Bb;
  __half* PW1 = Qb;
  __half* DW2 = Qb + PC;
  dw_kernel<256><<<4096, 256, 0, stream>>>(A, wdwT, DW1);
  pw1_kernel<<<512, 256, 0, stream>>>(DW1, WPW1, mb, PW1);
  dw_kernel<128><<<2048, 256, 0, stream>>>(PW1, pdwT, DW2);
  pw2_kernel<<<512, 256, 0, stream>>>(DW2, WPW2, pb, out);
}

// Round 14
// 260.555 us; speedup vs baseline: 1.0379x; 1.0379x over previous
//
#include <hip/hip_runtime.h>
#include <hip/hip_fp16.h>

// FlowLayer: B=2, CIN=256, COUT=128, H=W=128, iters=24.
// s = sum_{k=0..24} S^k m = m + S(t + S t),  t = (I+S^2)(I+S^4)(I+S^8+S^16) m
// 11 x S^2 (16-tap) + 2 x S (4-tap). S^2 kernel: 32 lanes/slot, x-adjacent tap
// PAIRS issued in one instruction (coalescer merges 2x256B -> 512B), partial
// sums combined via shfl_xor(16). Separate dw/pw merge kernels.
// (Round-12 best configuration: 260.7 us.)

#define PC 4194304
#define HW 16384

struct CoefC { int4 o0; float4 w0; int4 o1; float4 w1; int4 o2; float4 w2; int4 o3; float4 w3; };
struct Coef1 { int4 oa; float4 wa; };

struct alignas(16) H8 { __half2 h[4]; };
struct alignas(8)  H4 { __half2 h[2]; };
typedef _Float16 f16x8 __attribute__((ext_vector_type(8)));
typedef float f32x4 __attribute__((ext_vector_type(4)));

__device__ __forceinline__ float sigf(float v) { return 1.0f / (1.0f + __expf(-v)); }

__device__ __forceinline__ H8 f8h(const float* f) {
  H8 r;
#pragma unroll
  for (int i = 0; i < 4; i++) r.h[i] = __floats2half2_rn(f[2*i], f[2*i+1]);
  return r;
}
__device__ __forceinline__ f16x8 ld8(const __half* p) { return *(const f16x8*)p; }
__device__ __forceinline__ void fma8(float* a, const f16x8& v, float w) {
#pragma unroll
  for (int i = 0; i < 8; i++) a[i] = fmaf(w, (float)v[i], a[i]);   // v_fma_mix
}
__device__ __forceinline__ void fma4g(float* a, const f16x8& v0, const f16x8& v1,
                                      const f16x8& v2, const f16x8& v3, float4 w) {
  fma8(a, v0, w.x); fma8(a, v1, w.y); fma8(a, v2, w.z); fma8(a, v3, w.w);
}

// XCD-aware slot base (65536-slot space: 4 images of 16384; image -> XCD pair).
template <int SPB>
__device__ __forceinline__ int slot_base_64k(int bid) {
  int xcd = bid & 7;
  int i = xcd >> 1;
  int half = xcd & 1;
  int sub = bid >> 3;
  return (i >> 1) * 32768 + (i & 1) * 16384 + half * 8192 + sub * SPB;
}
// 32768-slot space (2 batches): image b -> 4 XCDs, each a quarter-image.
template <int SPB>
__device__ __forceinline__ int slot_base_32k(int bid) {
  int xcd = bid & 7;
  int b = xcd >> 2;
  int q = xcd & 3;
  int sub = bid >> 3;
  return b * 16384 + q * 4096 + sub * SPB;
}

// ---------------- per-pixel bilinear stencil
__device__ __forceinline__ void stencil(const float* __restrict__ g, float sgn, int pix,
                                        int4& op, float4& wt) {
  int b = pix >> 14, hw = pix & 16383;
  int h = hw >> 7, w = hw & 127;
  float gx = g[(size_t)(b * 2 + 0) * HW + hw];
  float gy = g[(size_t)(b * 2 + 1) * HW + hw];
  float xp = (float)w + sgn * gx;
  float yp = (float)h + sgn * gy;
  float x0f = floorf(xp), y0f = floorf(yp);
  float fx = xp - x0f, fy = yp - y0f;
  int x0 = (int)x0f, y0 = (int)y0f;
  int x1 = x0 + 1, y1 = y0 + 1;
  bool vx0 = (x0 >= 0) && (x0 <= 127);
  bool vx1 = (x1 >= 0) && (x1 <= 127);
  bool vy0 = (y0 >= 0) && (y0 <= 127);
  bool vy1 = (y1 >= 0) && (y1 <= 127);
  int x0c = min(max(x0, 0), 127), x1c = min(max(x1, 0), 127);
  int y0c = min(max(y0, 0), 127), y1c = min(max(y1, 0), 127);
  int bb = b << 14;
  op.x = bb + y0c * 128 + x0c;
  op.y = bb + y0c * 128 + x1c;
  op.z = bb + y1c * 128 + x0c;
  op.w = bb + y1c * 128 + x1c;
  wt.x = (vx0 && vy0) ? (1.f - fx) * (1.f - fy) : 0.f;
  wt.y = (vx1 && vy0) ? fx * (1.f - fy) : 0.f;
  wt.z = (vx0 && vy1) ? (1.f - fx) * fy : 0.f;
  wt.w = (vx1 && vy1) ? fx * fy : 0.f;
}

__device__ __forceinline__ int4 shl7(int4 v) {
  return make_int4(v.x << 7, v.y << 7, v.z << 7, v.w << 7);
}
__device__ __forceinline__ float4 scale4(float4 v, float s) {
  return make_float4(v.x * s, v.y * s, v.z * s, v.w * s);
}

// ---------------- merged prep: stencil tables + weight conversions
__global__ __launch_bounds__(256) void prep_kernel(const float* __restrict__ grads,
                                                   Coef1* __restrict__ c1,
                                                   CoefC* __restrict__ c2,
                                                   const float* __restrict__ mdw,
                                                   const float* __restrict__ pdw,
                                                   const float* __restrict__ w1,
                                                   const float* __restrict__ w2,
                                                   const float* __restrict__ mpw,
                                                   const float* __restrict__ ppw,
                                                   float* __restrict__ wdwT,
                                                   float* __restrict__ pdwT,
                                                   __half* __restrict__ wT16,
                                                   __half* __restrict__ wpw1,
                                                   __half* __restrict__ wpw2) {
  int bid = blockIdx.x;
  int tid = threadIdx.x;
  if (bid < 256) {
    int idx = bid * 256 + tid;
    int chain = idx >> 15;
    int p = idx & 32767;
    float sgn = chain ? -3.96875f : 3.96875f;   // 63.5*1.5/24
    int4 op; float4 ow;
    stencil(grads, sgn, p, op, ow);
    Coef1 a; a.oa = shl7(op); a.wa = ow;
    c1[idx] = a;
    CoefC c;
    int4 o2; float4 nw;
    stencil(grads, sgn, op.x, o2, nw); c.o0 = shl7(o2); c.w0 = scale4(nw, ow.x);
    stencil(grads, sgn, op.y, o2, nw); c.o1 = shl7(o2); c.w1 = scale4(nw, ow.y);
    stencil(grads, sgn, op.z, o2, nw); c.o2 = shl7(o2); c.w2 = scale4(nw, ow.z);
    stencil(grads, sgn, op.w, o2, nw); c.o3 = shl7(o2); c.w3 = scale4(nw, ow.w);
    c2[idx] = c;
  } else {
    int i = (bid - 256) * 256 + tid;
    if (i < 65536) {
      int co = i >> 8, ci = i & 255;
      float v = (co < 128) ? w1[co * 256 + ci] : w2[(size_t)(co - 128) * 256 + ci];
      wT16[i] = __float2half(v);
    } else if (i < 98304) {
      int j = i - 65536;
      wpw1[j] = __float2half(mpw[j]);
    } else if (i < 114688) {
      int j = i - 98304;
      wpw2[j] = __float2half(ppw[j]);
    } else if (i < 116992) {
      int j = i - 114688;
      int ch = j / 9, t = j % 9;
      wdwT[t * 256 + ch] = mdw[j];
    } else if (i < 118144) {
      int j = i - 116992;
      int ch = j / 9, t = j % 9;
      pdwT[t * 128 + ch] = pdw[j];
    }
  }
}

// ---------------- conv1x1 via f16 MFMA
__global__ __launch_bounds__(256) void conv1_kernel(const float* __restrict__ x,
                                                    const __half* __restrict__ wT16,
                                                    __half* __restrict__ mOut) {
  __shared__ __align__(16) char As[4096];
  __shared__ __align__(16) char Bs[16384];
  int tid = threadIdx.x;
  int p0 = blockIdx.x * 64;
  int b = p0 >> 14;
  int hw0 = p0 & 16383;
  int wv = tid >> 6, ln = tid & 63;
  int hi = ln >> 4, lo = ln & 15;
  f32x4 acc[4][4] = {};
  const float* xb = x + (size_t)b * 256 * HW + hw0;
  int apx = tid & 63, ac8 = (tid >> 6) * 8;
  int abyte = (apx * 64 + ac8 * 2) ^ ((apx & 3) << 4);
  for (int k = 0; k < 256; k += 32) {
    f16x8 av;
#pragma unroll
    for (int j = 0; j < 8; j++) av[j] = (_Float16)xb[(size_t)(k + ac8 + j) * HW + apx];
    if (k) __syncthreads();
    *(f16x8*)(As + abyte) = av;
    {
      const __half* src = wT16 + (size_t)tid * 256 + k;
#pragma unroll
      for (int s = 0; s < 4; s++) {
        f16x8 bv = *(const f16x8*)(src + s * 8);
        int byte = (tid * 64 + s * 16) ^ ((tid & 3) << 4);
        *(f16x8*)(Bs + byte) = bv;
      }
    }
    __syncthreads();
    f16x8 aF[4], bF[4];
#pragma unroll
    for (int m = 0; m < 4; m++) {
      int px = m * 16 + lo;
      int byte = (px * 64 + hi * 16) ^ ((px & 3) << 4);
      aF[m] = *(const f16x8*)(As + byte);
    }
#pragma unroll
    for (int n = 0; n < 4; n++) {
      int co = wv * 64 + n * 16 + lo;
      int byte = (co * 64 + hi * 16) ^ ((co & 3) << 4);
      bF[n] = *(const f16x8*)(Bs + byte);
    }
#pragma unroll
    for (int m = 0; m < 4; m++)
#pragma unroll
      for (int n = 0; n < 4; n++)
        acc[m][n] = __builtin_amdgcn_mfma_f32_16x16x32_f16(aF[m], bF[n], acc[m][n], 0, 0, 0);
  }
  size_t base = (wv >= 2) ? (size_t)PC : 0;
  int col0 = (wv & 1) * 64;
#pragma unroll
  for (int m = 0; m < 4; m++)
#pragma unroll
    for (int n = 0; n < 4; n++) {
      int col = col0 + n * 16 + lo;
#pragma unroll
      for (int rr = 0; rr < 4; rr++) {
        int px = p0 + m * 16 + hi * 4 + rr;
        mOut[base + (size_t)px * 128 + col] = __float2half(sigf(acc[m][n][rr]));
      }
    }
}

// ---------------- S^2 (16 taps as 8 x-adjacent PAIRS), 32 lanes/slot.
// Lanes 0-15 take the x0 row of each pair, lanes 16-31 the x1 row (same load
// instruction -> coalescer merges 512B). Partial sums combined via shfl_xor(16).
// ACC 0: none; 1: accOut = accAdd + res; 2: accOut += res; 3: acc only, no state write
template <int ACC>
__global__ __launch_bounds__(256) void s2_kernel(const __half* __restrict__ inb,
                                                 __half* __restrict__ outb,
                                                 const __half* __restrict__ accAdd,
                                                 __half* __restrict__ accOut,
                                                 const uint4* __restrict__ c2tab) {
  __shared__ uint4 cs[64];                   // 8 slots x 8 uint4
  int tid = threadIdx.x;
  int slot0 = slot_base_64k<8>(blockIdx.x);
  if (tid < 64) cs[tid] = c2tab[(size_t)slot0 * 8 + tid];
  __syncthreads();
  int sg = tid >> 5;                         // slot group 0..7
  int lane = tid & 31;
  int side = lane >> 4;                      // 0: x0 rows, 1: x1 rows
  int ch = (lane & 15) << 3;
  const CoefC c = ((const CoefC*)cs)[sg];
  int slot = slot0 + sg;
  int chain = slot >> 15;
  size_t cb = (size_t)chain * PC;
  const __half* base = inb + cb + ch;
  int rowel = ((slot & 32767) << 7) + ch;

  // 8 pairs: (o0.x,o0.y),(o0.z,o0.w),(o1.x,o1.y),(o1.z,o1.w),(o2...),(o3...)
  int o0 = side ? c.o0.y : c.o0.x;  float w0 = side ? c.w0.y : c.w0.x;
  int o1 = side ? c.o0.w : c.o0.z;  float w1 = side ? c.w0.w : c.w0.z;
  int o2 = side ? c.o1.y : c.o1.x;  float w2 = side ? c.w1.y : c.w1.x;
  int o3 = side ? c.o1.w : c.o1.z;  float w3 = side ? c.w1.w : c.w1.z;
  int o4 = side ? c.o2.y : c.o2.x;  float w4 = side ? c.w2.y : c.w2.x;
  int o5 = side ? c.o2.w : c.o2.z;  float w5 = side ? c.w2.w : c.w2.z;
  int o6 = side ? c.o3.y : c.o3.x;  float w6 = side ? c.w3.y : c.w3.x;
  int o7 = side ? c.o3.w : c.o3.z;  float w7 = side ? c.w3.w : c.w3.z;

  f16x8 v0 = ld8(base + o0), v1 = ld8(base + o1), v2 = ld8(base + o2), v3 = ld8(base + o3);
  f16x8 v4 = ld8(base + o4), v5 = ld8(base + o5), v6 = ld8(base + o6), v7 = ld8(base + o7);
  float a2[8] = {};
  fma8(a2, v0, w0); fma8(a2, v1, w1); fma8(a2, v2, w2); fma8(a2, v3, w3);
  fma8(a2, v4, w4); fma8(a2, v5, w5); fma8(a2, v6, w6); fma8(a2, v7, w7);
#pragma unroll
  for (int i = 0; i < 8; i++) a2[i] += __shfl_xor(a2[i], 16);   // combine x0/x1 halves

  if (side == 0) {
    if (ACC != 3) *(H8*)(outb + cb + rowel) = f8h(a2);
    if (ACC == 1 || ACC == 3) {
      f16x8 av = ld8(accAdd + cb + rowel);
      float af[8];
#pragma unroll
      for (int i = 0; i < 8; i++) af[i] = a2[i] + (float)av[i];
      *(H8*)(accOut + cb + rowel) = f8h(af);
    } else if (ACC == 2) {
      f16x8 av = ld8(accOut + cb + rowel);
      float af[8];
#pragma unroll
      for (int i = 0; i < 8; i++) af[i] = a2[i] + (float)av[i];
      *(H8*)(accOut + cb + rowel) = f8h(af);
    }
  }
}

// ---------------- single-S pass (4 taps). MODE 0: out = own + S in
// MODE 1: out = sigmoid(own + S in)
template <int MODE>
__global__ __launch_bounds__(256) void s1_kernel(const __half* __restrict__ tin,
                                                 const __half* __restrict__ own,
                                                 __half* __restrict__ outb,
                                                 const uint4* __restrict__ c1tab) {
  __shared__ uint4 cs[32];
  int tid = threadIdx.x;
  int slot0 = slot_base_64k<16>(blockIdx.x);
  if (tid < 32) cs[tid] = c1tab[(size_t)slot0 * 2 + tid];
  __syncthreads();
  const Coef1 a = ((const Coef1*)cs)[tid >> 4];
  int slot = slot0 + (tid >> 4);
  int ch = (tid & 15) << 3;
  int chain = slot >> 15;
  size_t cb = (size_t)chain * PC;
  const __half* base = tin + cb + ch;
  int rowel = ((slot & 32767) << 7) + ch;
  f16x8 t0 = ld8(base + a.oa.x), t1 = ld8(base + a.oa.y),
        t2 = ld8(base + a.oa.z), t3 = ld8(base + a.oa.w);
  f16x8 ov = ld8(own + cb + rowel);
  float r[8] = {};
  fma4g(r, t0, t1, t2, t3, a.wa);
  if (MODE == 0) {
#pragma unroll
    for (int i = 0; i < 8; i++) r[i] += (float)ov[i];
  } else {
#pragma unroll
    for (int i = 0; i < 8; i++) r[i] = sigf(r[i] + (float)ov[i]);
  }
  *(H8*)(outb + cb + rowel) = f8h(r);
}

// ---------------- depthwise 3x3, zero pad, XCD-local mapping, fma_mix
template <int C>
__global__ __launch_bounds__(256) void dw_kernel(const __half* __restrict__ in,
                                                 const float* __restrict__ wT,
                                                 __half* __restrict__ out) {
  int tid = threadIdx.x;
  constexpr int TPP = C / 8;
  constexpr int PPB = 256 / TPP;
  int slot = slot_base_32k<PPB>(blockIdx.x) + tid / TPP;
  int ch = (tid % TPP) * 8;
  int b = slot >> 14, h = (slot >> 7) & 127, w = slot & 127;
  const __half* src;
  int choff;
  if (C == 256) { src = in + ((ch < 128) ? 0 : (size_t)PC); choff = ch & 127; }
  else          { src = in; choff = ch; }
  float acc[8] = {};
#pragma unroll
  for (int t = 0; t < 9; t++) {
    int dy = t / 3 - 1, dx = t % 3 - 1;
    int yy = h + dy, xx = w + dx;
    if (yy < 0 || yy > 127 || xx < 0 || xx > 127) continue;
    int q = (b << 14) + yy * 128 + xx;
    f16x8 v = ld8(src + (size_t)q * 128 + choff);
    float4 wa = *(const float4*)(wT + t * C + ch);
    float4 wb = *(const float4*)(wT + t * C + ch + 4);
    acc[0] = fmaf(wa.x, (float)v[0], acc[0]);
    acc[1] = fmaf(wa.y, (float)v[1], acc[1]);
    acc[2] = fmaf(wa.z, (float)v[2], acc[2]);
    acc[3] = fmaf(wa.w, (float)v[3], acc[3]);
    acc[4] = fmaf(wb.x, (float)v[4], acc[4]);
    acc[5] = fmaf(wb.y, (float)v[5], acc[5]);
    acc[6] = fmaf(wb.z, (float)v[6], acc[6]);
    acc[7] = fmaf(wb.w, (float)v[7], acc[7]);
  }
  *(H8*)(out + (size_t)slot * C + ch) = f8h(acc);
}

// ---------------- pw1: [P]x[256] @ w[128co][256ci] -> fp16 channels-last [P][128]
__global__ __launch_bounds__(256) void pw1_kernel(const __half* __restrict__ in,
                                                  const __half* __restrict__ w16,
                                                  const float* __restrict__ bias,
                                                  __half* __restrict__ out) {
  int tid = threadIdx.x;
  int p0 = blockIdx.x * 64;
  int wv = tid >> 6, ln = tid & 63;
  int hi = ln >> 4, lo = ln & 15;
  int px = p0 + wv * 16 + lo;
  f32x4 acc[8] = {};
  for (int k = 0; k < 256; k += 32) {
    f16x8 bF = *(const f16x8*)(in + (size_t)px * 256 + k + hi * 8);
#pragma unroll
    for (int m = 0; m < 8; m++) {
      f16x8 aF = *(const f16x8*)(w16 + (size_t)(m * 16 + lo) * 256 + k + hi * 8);
      acc[m] = __builtin_amdgcn_mfma_f32_16x16x32_f16(aF, bF, acc[m], 0, 0, 0);
    }
  }
  int opx = p0 + wv * 16 + lo;
#pragma unroll
  for (int m = 0; m < 8; m++) {
    int co = m * 16 + hi * 4;
    float4 bv = *(const float4*)(bias + co);
    H4 hv;
    hv.h[0] = __floats2half2_rn(acc[m][0] + bv.x, acc[m][1] + bv.y);
    hv.h[1] = __floats2half2_rn(acc[m][2] + bv.z, acc[m][3] + bv.w);
    *(H4*)(out + (size_t)opx * 128 + co) = hv;
  }
}

// ---------------- pw2: [P]x[128] @ w[128co][128ci] -> f32 NCHW + bias
__global__ __launch_bounds__(256) void pw2_kernel(const __half* __restrict__ in,
                                                  const __half* __restrict__ w16,
                                                  const float* __restrict__ bias,
                                                  float* __restrict__ out) {
  int tid = threadIdx.x;
  int p0 = blockIdx.x * 64;
  int b = p0 >> 14;
  int hw0 = p0 & 16383;
  int wv = tid >> 6, ln = tid & 63;
  int hi = ln >> 4, lo = ln & 15;
  int co0 = wv * 32;
  f32x4 acc[4][2] = {};
  for (int k = 0; k < 128; k += 32) {
    f16x8 aF[4], bF[2];
#pragma unroll
    for (int m = 0; m < 4; m++)
      aF[m] = *(const f16x8*)(in + (size_t)(p0 + m * 16 + lo) * 128 + k + hi * 8);
#pragma unroll
    for (int n = 0; n < 2; n++)
      bF[n] = *(const f16x8*)(w16 + (size_t)(co0 + n * 16 + lo) * 128 + k + hi * 8);
#pragma unroll
    for (int m = 0; m < 4; m++)
#pragma unroll
      for (int n = 0; n < 2; n++)
        acc[m][n] = __builtin_amdgcn_mfma_f32_16x16x32_f16(aF[m], bF[n], acc[m][n], 0, 0, 0);
  }
#pragma unroll
  for (int m = 0; m < 4; m++)
#pragma unroll
    for (int n = 0; n < 2; n++) {
      int co = co0 + n * 16 + lo;
      float bb = bias[co];
      float4 v = {acc[m][n][0] + bb, acc[m][n][1] + bb, acc[m][n][2] + bb, acc[m][n][3] + bb};
      *(float4*)(out + (size_t)(b * 128 + co) * HW + hw0 + m * 16 + hi * 4) = v;
    }
}

extern "C" void kernel_launch(void* const* d_in, const int* in_sizes, int n_in,
                              void* d_out, int out_size, void* d_ws, size_t ws_size,
                              hipStream_t stream) {
  const float* x     = (const float*)d_in[0];
  const float* grads = (const float*)d_in[1];
  const float* w1    = (const float*)d_in[2];
  const float* w2    = (const float*)d_in[3];
  const float* mdw   = (const float*)d_in[4];
  const float* mpw   = (const float*)d_in[5];
  const float* mb    = (const float*)d_in[6];
  const float* pdw   = (const float*)d_in[7];
  const float* ppw   = (const float*)d_in[8];
  const float* pb    = (const float*)d_in[9];
  float* out = (float*)d_out;
  char* wsb = (char*)d_ws;

  __half* M  = (__half*)wsb;
  __half* A  = (__half*)(wsb + (size_t)16777216);
  __half* Bb = (__half*)(wsb + (size_t)33554432);
  __half* Pb = (__half*)(wsb + (size_t)50331648);
  __half* Qb = (__half*)(wsb + (size_t)67108864);
  CoefC* C2  = (CoefC*)(wsb + (size_t)83886080);
  Coef1* C1  = (Coef1*)(wsb + (size_t)92274688);
  __half* WT16 = (__half*)(wsb + (size_t)94371840);
  __half* WPW1 = (__half*)(wsb + (size_t)94502912);
  __half* WPW2 = (__half*)(wsb + (size_t)94568448);
  float* wdwT  = (float*)(wsb + (size_t)94601216);
  float* pdwT  = wdwT + 2304;

  const uint4* c2u = (const uint4*)C2;
  const uint4* c1u = (const uint4*)C1;

  prep_kernel<<<718, 256, 0, stream>>>(grads, C1, C2, mdw, pdw, w1, w2, mpw, ppw,
                                       wdwT, pdwT, WT16, WPW1, WPW2);
  conv1_kernel<<<512, 256, 0, stream>>>(x, WT16, M);

  // p = (I + S^8 + S^16) m   (P buffer)
  s2_kernel<0><<<8192, 256, 0, stream>>>(M,  A,  nullptr, nullptr, c2u);   // S^2 m
  s2_kernel<0><<<8192, 256, 0, stream>>>(A,  Bb, nullptr, nullptr, c2u);   // S^4
  s2_kernel<0><<<8192, 256, 0, stream>>>(Bb, A,  nullptr, nullptr, c2u);   // S^6
  s2_kernel<1><<<8192, 256, 0, stream>>>(A,  Bb, M,       Pb,      c2u);   // S^8 ; P=m+S^8m
  s2_kernel<0><<<8192, 256, 0, stream>>>(Bb, A,  nullptr, nullptr, c2u);   // S^10
  s2_kernel<0><<<8192, 256, 0, stream>>>(A,  Bb, nullptr, nullptr, c2u);   // S^12
  s2_kernel<0><<<8192, 256, 0, stream>>>(Bb, A,  nullptr, nullptr, c2u);   // S^14
  s2_kernel<2><<<8192, 256, 0, stream>>>(A,  Bb, nullptr, Pb,      c2u);   // S^16 ; P+=S^16m
  // q = (I + S^4) p ; t = (I + S^2) q
  s2_kernel<0><<<8192, 256, 0, stream>>>(Pb, A,  nullptr, nullptr, c2u);   // S^2 p
  s2_kernel<1><<<8192, 256, 0, stream>>>(A,  Bb, Pb,      Qb,      c2u);   // S^4 p ; Q=p+S^4p
  s2_kernel<3><<<8192, 256, 0, stream>>>(Qb, A,  Qb,      Pb,      c2u);   // t = q+S^2q (acc only)
  // s = sigmoid(m + S(t + S t)):  w = t + S t -> Bb ;  s = sigmoid(m + S w) -> A
  s1_kernel<0><<<4096, 256, 0, stream>>>(Pb, Pb, Bb, c1u);
  s1_kernel<1><<<4096, 256, 0, stream>>>(Bb, M,  A,  c1u);

  // merge stage (separate kernels)
  __half* DW1 = Bb;
  __half* PW1 = Qb;
  __half* DW2 = Qb + PC;
  dw_kernel<256><<<4096, 256, 0, stream>>>(A, wdwT, DW1);
  pw1_kernel<<<512, 256, 0, stream>>>(DW1, WPW1, mb, PW1);
  dw_kernel<128><<<2048, 256, 0, stream>>>(PW1, pdwT, DW2);
  pw2_kernel<<<512, 256, 0, stream>>>(DW2, WPW2, pb, out);
}